// Round 1
// baseline (319.307 us; speedup 1.0000x reference)
//
#include <hip/hip_runtime.h>

#define SCAN_BLOCK 1024

// Kernel 1: per-batch block scan over merge flags -> token segment boundaries.
// tok_start[b*(S+1) + t] = first subtoken index of token t; tok_start[..+ntok] = len.
__global__ void __launch_bounds__(SCAN_BLOCK)
scan_kernel(const int* __restrict__ merge,
            const int* __restrict__ lengths,
            int* __restrict__ tok_start,
            int* __restrict__ ntok_arr,
            int S) {
    const int b   = blockIdx.x;
    const int tid = threadIdx.x;
    const int per = (S + SCAN_BLOCK - 1) / SCAN_BLOCK;

    int len = lengths[b];
    if (len < 1) len = 1;
    if (len > S) len = S;

    const int* mrow = merge + (size_t)b * S;
    const int  base = tid * per;

    // pass 1: per-thread count of "new token" flags
    int tsum = 0;
    for (int i = 0; i < per; ++i) {
        int s = base + i;
        if (s < S) {
            int isnew = (s < len) && (s == 0 || mrow[s] == 0);
            tsum += isnew;
        }
    }

    // block-wide inclusive scan (Hillis-Steele in LDS; 10 steps, trivial cost)
    __shared__ int sums[SCAN_BLOCK];
    sums[tid] = tsum;
    __syncthreads();
    for (int off = 1; off < SCAN_BLOCK; off <<= 1) {
        int v = (tid >= off) ? sums[tid - off] : 0;
        __syncthreads();
        sums[tid] += v;
        __syncthreads();
    }

    // pass 2: emit start offsets at exclusive-prefix token ids
    int run = (tid > 0) ? sums[tid - 1] : 0;
    int* ts = tok_start + (size_t)b * (S + 1);
    for (int i = 0; i < per; ++i) {
        int s = base + i;
        if (s < S) {
            int isnew = (s < len) && (s == 0 || mrow[s] == 0);
            if (isnew) { ts[run] = s; ++run; }
        }
    }

    if (tid == SCAN_BLOCK - 1) {
        int ntok = sums[SCAN_BLOCK - 1];
        ntok_arr[b] = ntok;
        ts[ntok] = len;  // sentinel end for the last token
    }
}

// Kernel 2: one block per output row (b, t); 192 threads x float4 = 768 floats.
// Real tokens: mean over [start, end). Padding rows: write zeros (single write pass).
__global__ void __launch_bounds__(192)
mean_kernel(const float4* __restrict__ hidden,
            const int* __restrict__ tok_start,
            const int* __restrict__ ntok_arr,
            float4* __restrict__ out,
            int S, int D4) {
    const int t   = blockIdx.x;
    const int b   = blockIdx.y;
    const int tid = threadIdx.x;   // 0 .. D4-1

    const size_t orow = ((size_t)b * S + t) * (size_t)D4;
    const int ntok = ntok_arr[b];

    if (t >= ntok) {
        out[orow + tid] = make_float4(0.f, 0.f, 0.f, 0.f);
        return;
    }

    const int* ts   = tok_start + (size_t)b * (S + 1);
    const int start = ts[t];
    const int end   = ts[t + 1];

    const float4* h = hidden + (size_t)b * S * (size_t)D4;
    float4 acc = make_float4(0.f, 0.f, 0.f, 0.f);
    for (int s = start; s < end; ++s) {
        float4 v = h[(size_t)s * D4 + tid];
        acc.x += v.x; acc.y += v.y; acc.z += v.z; acc.w += v.w;
    }
    const float inv = 1.0f / (float)(end - start);
    out[orow + tid] = make_float4(acc.x * inv, acc.y * inv, acc.z * inv, acc.w * inv);
}

extern "C" void kernel_launch(void* const* d_in, const int* in_sizes, int n_in,
                              void* d_out, int out_size, void* d_ws, size_t ws_size,
                              hipStream_t stream) {
    const float* hidden  = (const float*)d_in[0];
    const int*   merge   = (const int*)d_in[1];
    const int*   lengths = (const int*)d_in[2];

    const int B  = in_sizes[2];          // 16
    const int BS = in_sizes[1];          // B*S
    const int S  = BS / B;               // 4096
    const int D  = in_sizes[0] / BS;     // 768
    const int D4 = D / 4;                // 192 (3 waves)

    int* tok_start = (int*)d_ws;                         // B*(S+1) ints (~262 KB)
    int* ntok      = tok_start + (size_t)B * (S + 1);    // B ints

    scan_kernel<<<B, SCAN_BLOCK, 0, stream>>>(merge, lengths, tok_start, ntok, S);
    mean_kernel<<<dim3(S, B), D4, 0, stream>>>((const float4*)hidden, tok_start, ntok,
                                               (float4*)d_out, S, D4);
}

// Round 3
// 311.795 us; speedup vs baseline: 1.0241x; 1.0241x over previous
//
#include <hip/hip_runtime.h>

typedef float vfloat4 __attribute__((ext_vector_type(4)));

#define SCAN_BLOCK 1024

// Kernel 1: per-batch block scan over merge flags -> token segment boundaries.
// tok_start[b*(S+1) + t] = first subtoken index of token t; tok_start[..+ntok] = len.
__global__ void __launch_bounds__(SCAN_BLOCK)
scan_kernel(const int* __restrict__ merge,
            const int* __restrict__ lengths,
            int* __restrict__ tok_start,
            int* __restrict__ ntok_arr,
            int S) {
    const int b   = blockIdx.x;
    const int tid = threadIdx.x;
    const int per = (S + SCAN_BLOCK - 1) / SCAN_BLOCK;

    int len = lengths[b];
    if (len < 1) len = 1;
    if (len > S) len = S;

    const int* mrow = merge + (size_t)b * S;
    const int  base = tid * per;

    // pass 1: per-thread count of "new token" flags
    int tsum = 0;
    for (int i = 0; i < per; ++i) {
        int s = base + i;
        if (s < S) {
            int isnew = (s < len) && (s == 0 || mrow[s] == 0);
            tsum += isnew;
        }
    }

    // block-wide inclusive scan (Hillis-Steele in LDS)
    __shared__ int sums[SCAN_BLOCK];
    sums[tid] = tsum;
    __syncthreads();
    for (int off = 1; off < SCAN_BLOCK; off <<= 1) {
        int v = (tid >= off) ? sums[tid - off] : 0;
        __syncthreads();
        sums[tid] += v;
        __syncthreads();
    }

    // pass 2: emit start offsets at exclusive-prefix token ids
    int run = (tid > 0) ? sums[tid - 1] : 0;
    int* ts = tok_start + (size_t)b * (S + 1);
    for (int i = 0; i < per; ++i) {
        int s = base + i;
        if (s < S) {
            int isnew = (s < len) && (s == 0 || mrow[s] == 0);
            if (isnew) { ts[run] = s; ++run; }
        }
    }

    if (tid == SCAN_BLOCK - 1) {
        int ntok = sums[SCAN_BLOCK - 1];
        ntok_arr[b] = ntok;
        ts[ntok] = len;  // sentinel end for the last token
    }
}

// Kernel 2: one WAVE per output row (b, t). Lane owns float4s {lane, lane+64, lane+128}
// of the 192-float4 row. 4 rows per 256-thread block. Segment loop unrolled x4 ->
// up to 12 independent nontemporal loads in flight per lane (hidden is read exactly
// once globally, output written once -> nt bypasses L2 allocation).
__global__ void __launch_bounds__(256)
mean_kernel(const vfloat4* __restrict__ hidden,
            const int* __restrict__ tok_start,
            const int* __restrict__ ntok_arr,
            vfloat4* __restrict__ out,
            int S) {
    const int wave = threadIdx.x >> 6;
    const int lane = threadIdx.x & 63;
    const int t    = (blockIdx.x << 2) + wave;   // token slot within batch
    const int b    = blockIdx.y;
    if (t >= S) return;

    vfloat4* op = out + ((size_t)b * S + t) * 192 + lane;
    const int ntok = ntok_arr[b];

    if (t >= ntok) {   // padding row: zeros (single write pass, no memset needed)
        const vfloat4 z = {0.f, 0.f, 0.f, 0.f};
        __builtin_nontemporal_store(z, op);
        __builtin_nontemporal_store(z, op + 64);
        __builtin_nontemporal_store(z, op + 128);
        return;
    }

    const int* ts   = tok_start + (size_t)b * (S + 1);
    const int start = ts[t];
    const int end   = ts[t + 1];

    const vfloat4* hp = hidden + (size_t)b * S * 192 + lane;

    vfloat4 a0 = {0.f, 0.f, 0.f, 0.f};
    vfloat4 a1 = a0, a2 = a0;

#define ACC_ROW(ROW)                                                     \
    {                                                                    \
        const vfloat4* p = hp + (size_t)(ROW) * 192;                     \
        vfloat4 v0 = __builtin_nontemporal_load(p);                      \
        vfloat4 v1 = __builtin_nontemporal_load(p + 64);                 \
        vfloat4 v2 = __builtin_nontemporal_load(p + 128);                \
        a0 += v0;                                                        \
        a1 += v1;                                                        \
        a2 += v2;                                                        \
    }

    int s = start;
    for (; s + 4 <= end; s += 4) {   // wave-uniform bounds -> uniform branch
        ACC_ROW(s)
        ACC_ROW(s + 1)
        ACC_ROW(s + 2)
        ACC_ROW(s + 3)
    }
    for (; s < end; ++s) {
        ACC_ROW(s)
    }
#undef ACC_ROW

    const float inv = 1.0f / (float)(end - start);
    a0 *= inv;
    a1 *= inv;
    a2 *= inv;
    __builtin_nontemporal_store(a0, op);
    __builtin_nontemporal_store(a1, op + 64);
    __builtin_nontemporal_store(a2, op + 128);
}

extern "C" void kernel_launch(void* const* d_in, const int* in_sizes, int n_in,
                              void* d_out, int out_size, void* d_ws, size_t ws_size,
                              hipStream_t stream) {
    const float* hidden  = (const float*)d_in[0];
    const int*   merge   = (const int*)d_in[1];
    const int*   lengths = (const int*)d_in[2];

    const int B  = in_sizes[2];          // 16
    const int BS = in_sizes[1];          // B*S
    const int S  = BS / B;               // 4096
    // D assumed 768 (vfloat4 x 192 per row), per reference shapes.

    int* tok_start = (int*)d_ws;                         // B*(S+1) ints (~262 KB)
    int* ntok      = tok_start + (size_t)B * (S + 1);    // B ints

    scan_kernel<<<B, SCAN_BLOCK, 0, stream>>>(merge, lengths, tok_start, ntok, S);
    mean_kernel<<<dim3((S + 3) / 4, B), 256, 0, stream>>>((const vfloat4*)hidden,
                                                          tok_start, ntok,
                                                          (vfloat4*)d_out, S);
}